// Round 7
// baseline (697.305 us; speedup 1.0000x reference)
//
#include <hip/hip_runtime.h>

// Problem constants (fixed by the reference)
#define N_ROWS 262144
#define D 80           // input feature dim
#define DA 81          // augmented dim [x, 1]
#define MSTRIDE 84     // column stride for bilinear matrices
#define DOUT 160
#define EPS 1e-5f

// ws layout (in floats)
#define S_OFF   0                      // 3 x (81*81) second-moment matrices (UPPER TRIANGLE valid)
#define S_SIZE  (DA * DA)              // 6561
#define T_OFF   (3 * S_SIZE)           // T = W~ @ S~  (3 x 160x81)
#define T_SIZE  (DOUT * DA)
#define WP_OFF  (T_OFF + 3 * T_SIZE)   // W' effective weights (3 x 160x81)
#define WP_SIZE (DOUT * DA)
#define MC_OFF  ((WP_OFF + 3 * WP_SIZE + 3) & ~3) // Mc[q][k*84+i] = M_q[i,k]
#define MC_SIZE (DA * MSTRIDE)
#define AUG_OFF (MC_OFF + 3 * MC_SIZE) // aug[q][k] = M_q[i=80, k]  (3 x 84)
#define AUG_SIZE 84

// ---------------------------------------------------------------------------
// K1: per-input augmented second moments S~ = sum_rows [x,1][x,1]^T
//     Double-buffered LDS staging, 512 blocks/input, upper-triangle atomics.
//     (unchanged this round; k3 v3 should drop below k1 so k1's counters
//      surface in the next profile)
// ---------------------------------------------------------------------------
#define K1_BLOCKS 512
#define K1_ROWS   (N_ROWS / K1_BLOCKS)   // 512 rows/block
#define K1_NT     (K1_ROWS / 32)         // 16 tiles of 32 rows

__global__ __launch_bounds__(256) void k1_moments(const float* __restrict__ xs,
                                                  const float* __restrict__ xl,
                                                  const float* __restrict__ xr,
                                                  float* __restrict__ ws) {
    const float* x = (blockIdx.y == 0) ? xs : (blockIdx.y == 1) ? xl : xr;
    float* S = ws + S_OFF + blockIdx.y * S_SIZE;

    __shared__ float lds[2 * 2560 + 3600];   // 34.9 KB

    const int tid = threadIdx.x;
    const int wave = tid >> 6;
    const int lane = tid & 63;

    int ti = -1, tj = -1;
    if (lane < 55) {
        int l = lane, a = 0;
        while (l >= 10 - a) { l -= 10 - a; a++; }
        ti = a; tj = a + l;
    }

    float acc[8][8];
#pragma unroll
    for (int u = 0; u < 8; u++)
#pragma unroll
        for (int v = 0; v < 8; v++) acc[u][v] = 0.f;
    float csum[8];
#pragma unroll
    for (int u = 0; u < 8; u++) csum[u] = 0.f;

    const size_t base = (size_t)blockIdx.x * K1_ROWS * D;
    const float4* __restrict__ gsrc = reinterpret_cast<const float4*>(x + base);

    float4 r0, r1, r2;
    r0 = gsrc[tid]; r1 = gsrc[tid + 256]; if (tid < 128) r2 = gsrc[tid + 512];
    {
        float4* d4 = reinterpret_cast<float4*>(lds);
        d4[tid] = r0; d4[tid + 256] = r1; if (tid < 128) d4[tid + 512] = r2;
    }

    for (int t = 0; t < K1_NT; t++) {
        __syncthreads();
        if (t + 1 < K1_NT) {
            const float4* __restrict__ s = gsrc + (size_t)(t + 1) * 640;
            r0 = s[tid]; r1 = s[tid + 256]; if (tid < 128) r2 = s[tid + 512];
        }
        const float* __restrict__ buf = lds + (t & 1) * 2560;
        if (ti >= 0) {
            const int rbase = wave * 8;
#pragma unroll 2
            for (int rr = 0; rr < 8; rr++) {
                const float* row = &buf[(rbase + rr) * D];
                float a8[8], b8[8];
                *reinterpret_cast<float4*>(&a8[0]) = *reinterpret_cast<const float4*>(&row[ti * 8]);
                *reinterpret_cast<float4*>(&a8[4]) = *reinterpret_cast<const float4*>(&row[ti * 8 + 4]);
                *reinterpret_cast<float4*>(&b8[0]) = *reinterpret_cast<const float4*>(&row[tj * 8]);
                *reinterpret_cast<float4*>(&b8[4]) = *reinterpret_cast<const float4*>(&row[tj * 8 + 4]);
#pragma unroll
                for (int u = 0; u < 8; u++)
#pragma unroll
                    for (int v = 0; v < 8; v++) acc[u][v] += a8[u] * b8[v];
                if (ti == tj) {
#pragma unroll
                    for (int u = 0; u < 8; u++) csum[u] += a8[u];
                }
            }
        }
        if (t + 1 < K1_NT) {
            float4* d4 = reinterpret_cast<float4*>(lds + ((t + 1) & 1) * 2560);
            d4[tid] = r0; d4[tid + 256] = r1; if (tid < 128) d4[tid + 512] = r2;
        }
    }

    float* red = lds + 5120;
    __syncthreads();
    for (int i = tid; i < 3600; i += 256) red[i] = 0.f;
    __syncthreads();
    for (int w = 0; w < 4; w++) {
        if (wave == w && ti >= 0) {
            float* dst = &red[lane * 64];
#pragma unroll
            for (int u = 0; u < 8; u++)
#pragma unroll
                for (int v = 0; v < 8; v++) dst[u * 8 + v] += acc[u][v];
            if (ti == tj) {
#pragma unroll
                for (int u = 0; u < 8; u++) red[3520 + ti * 8 + u] += csum[u];
            }
        }
        __syncthreads();
    }

    // global atomics: UPPER TRIANGLE ONLY (no mirrors)
    for (int e = tid; e < 3520; e += 256) {
        int p = e >> 6, o = e & 63;
        int l = p, a = 0;
        while (l >= 10 - a) { l -= 10 - a; a++; }
        const int pi = a, pj = a + l;
        const int i = pi * 8 + (o >> 3), j = pj * 8 + (o & 7);
        atomicAdd(&S[i * DA + j], red[e]);
    }
    for (int c = tid; c < D; c += 256) {
        atomicAdd(&S[c * DA + D], red[3520 + c]);  // column 80 (upper)
    }
    // corner S[80,80] = N handled inline in k2_T
}

// ---------------------------------------------------------------------------
// K2a: T[p][j][i] = sum_k W~[j,k] * S~[k,i]   (W~ = [W | b])
//      S is stored upper-triangle-only: S~[k,i] = S[min(k,i)*DA + max(k,i)]
// ---------------------------------------------------------------------------
__global__ void k2_T(const float* __restrict__ Ws, const float* __restrict__ bs,
                     const float* __restrict__ Wl, const float* __restrict__ bl,
                     const float* __restrict__ Wr, const float* __restrict__ br,
                     float* __restrict__ ws) {
    int e = blockIdx.x * 256 + threadIdx.x;
    if (e >= 3 * DOUT * DA) return;
    int p = e / (DOUT * DA);
    int rem = e - p * (DOUT * DA);
    int j = rem / DA, i = rem - j * DA;

    const float* W = (p == 0) ? Ws : (p == 1) ? Wl : Wr;
    const float* b = (p == 0) ? bs : (p == 1) ? bl : br;
    const float* S = ws + S_OFF + p * S_SIZE;

    float a0 = 0.f;
    const int kmid = (i < D) ? (i + 1) : D;
    for (int k = 0; k < kmid; k++)          // k <= i: (k,i) is upper
        a0 += W[j * D + k] * S[k * DA + i];
    for (int k = kmid; k < D; k++)          // k > i: read (i,k)
        a0 += W[j * D + k] * S[i * DA + k];
    float s80 = (i == D) ? (float)N_ROWS : S[i * DA + D];
    ws[T_OFF + p * T_SIZE + j * DA + i] = a0 + b[j] * s80;
}

// ---------------------------------------------------------------------------
// K2b: per feature j: mu, var, a -> effective W'[j,:] (augmented)
// ---------------------------------------------------------------------------
__global__ void k2_scale(const float* __restrict__ Ws, const float* __restrict__ bs,
                         const float* __restrict__ gs, const float* __restrict__ bes,
                         const float* __restrict__ Wl, const float* __restrict__ bl,
                         const float* __restrict__ gl, const float* __restrict__ bel,
                         const float* __restrict__ Wr, const float* __restrict__ br,
                         const float* __restrict__ gr, const float* __restrict__ ber,
                         float* __restrict__ ws) {
    int e = blockIdx.x * 256 + threadIdx.x;
    if (e >= 3 * DOUT) return;
    int p = e / DOUT, j = e - p * DOUT;

    const float* W  = (p == 0) ? Ws  : (p == 1) ? Wl  : Wr;
    const float* b  = (p == 0) ? bs  : (p == 1) ? bl  : br;
    const float* g  = (p == 0) ? gs  : (p == 1) ? gl  : gr;
    const float* be = (p == 0) ? bes : (p == 1) ? bel : ber;

    const float* T = ws + T_OFF + p * T_SIZE + j * DA;
    float eh2 = 0.f;
    for (int k = 0; k < D; k++) eh2 += T[k] * W[j * D + k];
    eh2 += T[D] * b[j];
    const float invN = 1.0f / (float)N_ROWS;
    eh2 *= invN;
    float mu = T[D] * invN;
    float var = eh2 - mu * mu;
    float a = g[j] * rsqrtf(var + EPS);

    float* Wp = ws + WP_OFF + p * WP_SIZE + j * DA;
    for (int k = 0; k < D; k++) Wp[k] = a * W[j * D + k];
    Wp[D] = a * b[j] + be[j] - a * mu;
}

// ---------------------------------------------------------------------------
// K2c: bilinear matrices Mc[q][k*84+i] = M_q[i,k] = sum_j W'_a[j,i] * W'_b[j,k]
//      q=0: (a=sub,  b=left )   q=1: (a=sub, b=right)   q=2: (a=left, b=right)
//      Also emits the compact aug row aug[q][k] = M_q[80,k].
// ---------------------------------------------------------------------------
__global__ void k2_M(float* __restrict__ ws) {
    int e = blockIdx.x * 256 + threadIdx.x;
    if (e >= 3 * DA * DA) return;
    int q = e / (DA * DA);
    int rem = e - q * (DA * DA);
    int k = rem / DA, i = rem - k * DA;

    int pa = (q == 2) ? 1 : 0;  // i-side: sub, sub, left
    int pb = (q == 0) ? 1 : 2;  // k-side: left, right, right
    const float* Wa = ws + WP_OFF + pa * WP_SIZE;
    const float* Wb = ws + WP_OFF + pb * WP_SIZE;

    float a0 = 0.f, a1 = 0.f;
    for (int j = 0; j < DOUT; j += 2) {
        a0 += Wa[j * DA + i] * Wb[j * DA + k];
        a1 += Wa[(j + 1) * DA + i] * Wb[(j + 1) * DA + k];
    }
    float v = a0 + a1;
    ws[MC_OFF + q * MC_SIZE + k * MSTRIDE + i] = v;
    if (i == D) ws[AUG_OFF + q * AUG_SIZE + k] = v;   // row i=80 compact copy
}

// ---------------------------------------------------------------------------
// K3 (fused tiled GEMM, v3): mapping + swizzle changes vs v2 (which verified
// the structure at 281us):
//   - Thread mapping swapped: ig = tid>>4, rg = tid&15.  A wave now holds 4
//     CONTIGUOUS ig groups -> each M global_load_dwordx4 touches one 64B
//     chunk (1 L1 line) instead of 20 chunks / ~6 lines: 6x less L1-line
//     traffic on the dominant load stream (84 loads/thread/pass).
//   - X stored with rotation swizzle: logical quad c4 of row r lives at slot
//     (c4 + (r>>2)) % 20.  With rg varying inside a wave, unswizzled reads
//     would be 8-way bank conflicts; rotated starts cover all 32 banks at
//     <=2-way (free).  XLD=80, no pad -> X=20KB; LDS total 31744B -> still
//     5 blocks/CU.
// ---------------------------------------------------------------------------
#define G_IG   20
#define G_RG   16
#define G_RT   4
#define G_ROWS (G_RG * G_RT)        // 64
#define G_TPB  (G_IG * G_RG)        // 320
#define XLD    80                   // floats per LDS row (no pad; swizzled)
#define SRED_LD 20

__device__ __forceinline__ void gemm_pass(const float* __restrict__ Mc,
                                          const float* __restrict__ augq,  // ws+AUG_OFF+q*AUG_SIZE
                                          const float* __restrict__ X,     // LDS k-side tile (swizzled)
                                          const float4* __restrict__ dot4, // global i-side rows (20 float4/row)
                                          int ig, int rg,
                                          float* __restrict__ sred) {
    const int i0 = ig * 4;
    float z[G_RT][4];
#pragma unroll
    for (int r = 0; r < G_RT; r++) { z[r][0] = z[r][1] = z[r][2] = z[r][3] = 0.f; }

#pragma unroll 2
    for (int kb = 0; kb < 20; kb++) {
        int sl = kb + rg; if (sl >= 20) sl -= 20;   // swizzled slot of col-quad kb for rows r>>2==rg
        float4 m0 = *reinterpret_cast<const float4*>(&Mc[(kb * 4 + 0) * MSTRIDE + i0]);
        float4 m1 = *reinterpret_cast<const float4*>(&Mc[(kb * 4 + 1) * MSTRIDE + i0]);
        float4 m2 = *reinterpret_cast<const float4*>(&Mc[(kb * 4 + 2) * MSTRIDE + i0]);
        float4 m3 = *reinterpret_cast<const float4*>(&Mc[(kb * 4 + 3) * MSTRIDE + i0]);
#pragma unroll
        for (int r = 0; r < G_RT; r++) {
            float4 xk = *reinterpret_cast<const float4*>(&X[(rg * G_RT + r) * XLD + sl * 4]);
            z[r][0] += m0.x * xk.x; z[r][1] += m0.y * xk.x; z[r][2] += m0.z * xk.x; z[r][3] += m0.w * xk.x;
            z[r][0] += m1.x * xk.y; z[r][1] += m1.y * xk.y; z[r][2] += m1.z * xk.y; z[r][3] += m1.w * xk.y;
            z[r][0] += m2.x * xk.z; z[r][1] += m2.y * xk.z; z[r][2] += m2.z * xk.z; z[r][3] += m2.w * xk.z;
            z[r][0] += m3.x * xk.w; z[r][1] += m3.y * xk.w; z[r][2] += m3.z * xk.w; z[r][3] += m3.w * xk.w;
        }
    }
    {   // k = 80 column term (x_b~[r,80] = 1)
        float4 m80 = *reinterpret_cast<const float4*>(&Mc[D * MSTRIDE + i0]);
#pragma unroll
        for (int r = 0; r < G_RT; r++) {
            z[r][0] += m80.x; z[r][1] += m80.y; z[r][2] += m80.z; z[r][3] += m80.w;
        }
    }
    // dot with i-side rows + fold this thread's aug-row chunk; write partial
    float4 av = *reinterpret_cast<const float4*>(&augq[i0]);   // global, L1-hot
    int slA = ig + rg; if (slA >= 20) slA -= 20;               // slot of col-quad ig
#pragma unroll
    for (int r = 0; r < G_RT; r++) {
        const int row = rg * G_RT + r;
        float4 xa = *reinterpret_cast<const float4*>(&X[row * XLD + slA * 4]);
        float4 w4 = dot4[row * 20 + ig];
        sred[row * SRED_LD + ig] =
            z[r][0] * w4.x + z[r][1] * w4.y + z[r][2] * w4.z + z[r][3] * w4.w
            + av.x * xa.x + av.y * xa.y + av.z * xa.z + av.w * xa.w;
    }
}

__global__ __launch_bounds__(G_TPB, 6) void k3_main(const float* __restrict__ xs_g,
                                                    const float* __restrict__ xl_g,
                                                    const float* __restrict__ xr_g,
                                                    const float* __restrict__ ws,
                                                    float* __restrict__ out) {
    __shared__ __align__(16) float X[G_ROWS * XLD];          // 20480 B
    __shared__ __align__(16) float sredA[G_ROWS * SRED_LD];  //  5120 B
    __shared__ __align__(16) float sredB[G_ROWS * SRED_LD];  //  5120 B
    __shared__ __align__(16) float parr[G_ROWS * 4];         //  1024 B -> 31744 B total

    const int tid = threadIdx.x;
    const int ig = tid >> 4;      // 0..19, wave-contiguous (M-load coalescing)
    const int rg = tid & 15;      // 0..15
    const size_t rowBase = (size_t)blockIdx.x * G_ROWS;

    const float* Mc0 = ws + MC_OFF + 0 * MC_SIZE;
    const float* Mc1 = ws + MC_OFF + 1 * MC_SIZE;
    const float* Mc2 = ws + MC_OFF + 2 * MC_SIZE;
    const float* aug0 = ws + AUG_OFF + 0 * AUG_SIZE;
    const float* aug1 = ws + AUG_OFF + 1 * AUG_SIZE;
    const float* aug2 = ws + AUG_OFF + 2 * AUG_SIZE;

    const float4* gl = reinterpret_cast<const float4*>(xl_g + rowBase * D);
    const float4* gr = reinterpret_cast<const float4*>(xr_g + rowBase * D);
    const float4* gs = reinterpret_cast<const float4*>(xs_g + rowBase * D);

    float s0r = 0.f, s1r, s2r;   // meaningful on tid < 64 only

    // ---- stage LEFT tile (swizzled) ----
#pragma unroll
    for (int it = 0; it < 4; it++) {
        int u = tid + it * G_TPB;          // < 1280
        int r = u / 20, c4 = u % 20;
        int sl = c4 + (r >> 2); if (sl >= 20) sl -= 20;
        *reinterpret_cast<float4*>(&X[r * XLD + sl * 4]) = gl[u];
    }
    __syncthreads();

    // ---- pass 0: M_sl x left, dot = sub ----
    gemm_pass(Mc0, aug0, X, gs, ig, rg, sredA);
    __syncthreads();

    // ---- reduce s0 (wave 0) || stage RIGHT tile (all threads) ----
    if (tid < G_ROWS) {
        float a = aug0[D];                 // M_sl[80,80], uniform scalar
#pragma unroll
        for (int c = 0; c < SRED_LD; c++) a += sredA[tid * SRED_LD + c];
        s0r = a;
    }
#pragma unroll
    for (int it = 0; it < 4; it++) {
        int u = tid + it * G_TPB;
        int r = u / 20, c4 = u % 20;
        int sl = c4 + (r >> 2); if (sl >= 20) sl -= 20;
        *reinterpret_cast<float4*>(&X[r * XLD + sl * 4]) = gr[u];
    }
    __syncthreads();

    // ---- passes 1 & 2 back-to-back (both k-side = right; disjoint sred) ----
    gemm_pass(Mc1, aug1, X, gs, ig, rg, sredA);   // dot = sub
    gemm_pass(Mc2, aug2, X, gl, ig, rg, sredB);   // dot = left
    __syncthreads();

    // ---- reduce s1,s2 + softmax (wave 0) ----
    if (tid < G_ROWS) {
        float a = aug1[D];
        float b = aug2[D];
#pragma unroll
        for (int c = 0; c < SRED_LD; c++) {
            a += sredA[tid * SRED_LD + c];
            b += sredB[tid * SRED_LD + c];
        }
        s1r = a; s2r = b;
        float m = fmaxf(s0r, fmaxf(s1r, s2r));
        float e0 = __expf(s0r - m), e1 = __expf(s1r - m), e2 = __expf(s2r - m);
        float inv = 1.0f / (e0 + e1 + e2);
        parr[tid * 4 + 0] = e0 * inv;   // weight for left
        parr[tid * 4 + 1] = e1 * inv;   // weight for right
        parr[tid * 4 + 2] = e2 * inv;   // weight for sub
    }
    __syncthreads();

    // ---- combine + store (right from LDS X; left/sub from global L2-hot) ----
    {
        float4* go = reinterpret_cast<float4*>(out + rowBase * D);
#pragma unroll
        for (int it = 0; it < 4; it++) {
            int u = tid + it * G_TPB;
            int r = u / 20, c4 = u % 20;
            int sl = c4 + (r >> 2); if (sl >= 20) sl -= 20;
            float p0 = parr[r * 4 + 0], p1 = parr[r * 4 + 1], p2 = parr[r * 4 + 2];
            float4 L = gl[u];
            float4 R = *reinterpret_cast<const float4*>(&X[r * XLD + sl * 4]);
            float4 S = gs[u];
            float4 o;
            o.x = p0 * L.x + p1 * R.x + p2 * S.x;
            o.y = p0 * L.y + p1 * R.y + p2 * S.y;
            o.z = p0 * L.z + p1 * R.z + p2 * S.z;
            o.w = p0 * L.w + p1 * R.w + p2 * S.w;
            go[u] = o;
        }
    }
}

// ---------------------------------------------------------------------------
extern "C" void kernel_launch(void* const* d_in, const int* in_sizes, int n_in,
                              void* d_out, int out_size, void* d_ws, size_t ws_size,
                              hipStream_t stream) {
    const float* xs = (const float*)d_in[0];
    const float* xl = (const float*)d_in[1];
    const float* xr = (const float*)d_in[2];
    const float* Wsub = (const float*)d_in[3];
    const float* bsub = (const float*)d_in[4];
    const float* gsub = (const float*)d_in[5];
    const float* besub = (const float*)d_in[6];
    const float* Wleft = (const float*)d_in[7];
    const float* bleft = (const float*)d_in[8];
    const float* gleft = (const float*)d_in[9];
    const float* beleft = (const float*)d_in[10];
    const float* Wright = (const float*)d_in[11];
    const float* bright = (const float*)d_in[12];
    const float* gright = (const float*)d_in[13];
    const float* beright = (const float*)d_in[14];
    float* ws = (float*)d_ws;
    float* out = (float*)d_out;

    hipMemsetAsync(ws + S_OFF, 0, 3 * S_SIZE * sizeof(float), stream);

    k1_moments<<<dim3(K1_BLOCKS, 3), 256, 0, stream>>>(xs, xl, xr, ws);
    k2_T<<<(3 * DOUT * DA + 255) / 256, 256, 0, stream>>>(
        Wsub, bsub, Wleft, bleft, Wright, bright, ws);
    k2_scale<<<(3 * DOUT + 255) / 256, 256, 0, stream>>>(
        Wsub, bsub, gsub, besub, Wleft, bleft, gleft, beleft,
        Wright, bright, gright, beright, ws);
    k2_M<<<(3 * DA * DA + 255) / 256, 256, 0, stream>>>(ws);
    k3_main<<<N_ROWS / G_ROWS, G_TPB, 0, stream>>>(xs, xl, xr, ws, out);
}